// Round 3
// baseline (568.392 us; speedup 1.0000x reference)
//
#include <hip/hip_runtime.h>
#include <hip/hip_fp16.h>
#include <stdint.h>

#define D 256
#define BM 128
#define BN 128
#define BK 32
#define LDK 40   // padded LDS row length in fp16 elems (32 data + 8 pad)

typedef _Float16 f16x8 __attribute__((ext_vector_type(8)));
typedef float f32x4 __attribute__((ext_vector_type(4)));

__device__ __forceinline__ uint32_t fmono(float f) {
    uint32_t u = __float_as_uint(f);
    return (u & 0x80000000u) ? ~u : (u | 0x80000000u);
}

// ---------------- prep: f64 norms + fp16 hi/scaled-lo split + init keys/hist ----------------
__global__ void prep_kernel(const float* __restrict__ X, const float* __restrict__ E,
                            double* __restrict__ xn, double* __restrict__ en,
                            unsigned short* __restrict__ Xh, unsigned short* __restrict__ Xl,
                            unsigned short* __restrict__ Eh, unsigned short* __restrict__ El,
                            unsigned long long* __restrict__ keys,
                            unsigned int* __restrict__ hist, int N, int K)
{
    int gid  = blockIdx.x * blockDim.x + threadIdx.x;
    int wid  = gid >> 6;
    int lane = threadIdx.x & 63;
    if (wid < N + K) {
        bool isX = wid < N;
        int r = isX ? wid : wid - N;
        const float* src = isX ? (X + (size_t)r * D) : (E + (size_t)r * D);
        float4 v = *(const float4*)(src + lane * 4);
        double s = (double)v.x*v.x + (double)v.y*v.y + (double)v.z*v.z + (double)v.w*v.w;
        #pragma unroll
        for (int o = 32; o >= 1; o >>= 1) s += __shfl_xor(s, o, 64);

        ushort4 h4, l4;
        {
            __half h;
            h = __float2half_rn(v.x); h4.x = __half_as_ushort(h);
            l4.x = __half_as_ushort(__float2half_rn((v.x - __half2float(h)) * 4096.0f));
            h = __float2half_rn(v.y); h4.y = __half_as_ushort(h);
            l4.y = __half_as_ushort(__float2half_rn((v.y - __half2float(h)) * 4096.0f));
            h = __float2half_rn(v.z); h4.z = __half_as_ushort(h);
            l4.z = __half_as_ushort(__float2half_rn((v.z - __half2float(h)) * 4096.0f));
            h = __float2half_rn(v.w); h4.w = __half_as_ushort(h);
            l4.w = __half_as_ushort(__float2half_rn((v.w - __half2float(h)) * 4096.0f));
        }
        size_t off = (size_t)r * D + lane * 4;
        if (isX) {
            *(ushort4*)(Xh + off) = h4; *(ushort4*)(Xl + off) = l4;
            if (lane == 0) xn[r] = s;
        } else {
            *(ushort4*)(Eh + off) = h4; *(ushort4*)(El + off) = l4;
            if (lane == 0) en[r] = s;
        }
    }
    int stride = gridDim.x * blockDim.x;
    for (int i = gid; i < N; i += stride) keys[i] = 0xFFFFFFFFFFFFFFFFull;
    for (int i = gid; i < K; i += stride) hist[i] = 0u;
}

// ---------------- dist via fp16x2-split MFMA (hh + 2^-12 * cross) ----------------
__global__ __launch_bounds__(256, 2) void dist_mfma(
    const unsigned short* __restrict__ Xh, const unsigned short* __restrict__ Xl,
    const unsigned short* __restrict__ Eh, const unsigned short* __restrict__ El,
    const double* __restrict__ xn, const double* __restrict__ en,
    float* __restrict__ dist, unsigned long long* __restrict__ keys,
    int N, int K)
{
    __shared__ unsigned short sAh[BM * LDK];
    __shared__ unsigned short sAl[BM * LDK];
    __shared__ unsigned short sBh[BN * LDK];
    __shared__ unsigned short sBl[BN * LDK];

    const int tid  = threadIdx.x;
    const int lane = tid & 63;
    const int wv   = tid >> 6;
    const int wrow = (wv & 1) * 64;
    const int wcol = (wv >> 1) * 64;
    const int row0 = blockIdx.y * BM;
    const int col0 = blockIdx.x * BN;

    const int rS = tid >> 2;            // 0..63 (it adds +64)
    const int sS = (tid & 3) * 8;       // ushort offset within row
    const size_t rowskip = (size_t)64 * D;
    const unsigned short* pXh = Xh + (size_t)(row0 + rS) * D + sS;
    const unsigned short* pXl = Xl + (size_t)(row0 + rS) * D + sS;
    const unsigned short* pEh = Eh + (size_t)(col0 + rS) * D + sS;
    const unsigned short* pEl = El + (size_t)(col0 + rS) * D + sS;
    const int ldso = rS * LDK + sS;

    f32x4 acc[4][4];   // hh
    f32x4 acr[4][4];   // cross (scaled by 2^12)
    #pragma unroll
    for (int i = 0; i < 4; ++i)
        #pragma unroll
        for (int j = 0; j < 4; ++j) { acc[i][j] = {0.f,0.f,0.f,0.f}; acr[i][j] = {0.f,0.f,0.f,0.f}; }

    uint4 gah[2], gal[2], gbh[2], gbl[2];
    #pragma unroll
    for (int it = 0; it < 2; ++it) {
        gah[it] = *(const uint4*)(pXh + it * rowskip);
        gal[it] = *(const uint4*)(pXl + it * rowskip);
        gbh[it] = *(const uint4*)(pEh + it * rowskip);
        gbl[it] = *(const uint4*)(pEl + it * rowskip);
    }

    const int fr = lane & 15;
    const int kq = (lane >> 4) * 8;

    for (int c = 0; c < D / BK; ++c) {
        __syncthreads();
        #pragma unroll
        for (int it = 0; it < 2; ++it) {
            *(uint4*)&sAh[ldso + it * 64 * LDK] = gah[it];
            *(uint4*)&sAl[ldso + it * 64 * LDK] = gal[it];
            *(uint4*)&sBh[ldso + it * 64 * LDK] = gbh[it];
            *(uint4*)&sBl[ldso + it * 64 * LDK] = gbl[it];
        }
        __syncthreads();
        if (c + 1 < D / BK) {
            int cc = (c + 1) * BK;
            #pragma unroll
            for (int it = 0; it < 2; ++it) {
                gah[it] = *(const uint4*)(pXh + it * rowskip + cc);
                gal[it] = *(const uint4*)(pXl + it * rowskip + cc);
                gbh[it] = *(const uint4*)(pEh + it * rowskip + cc);
                gbl[it] = *(const uint4*)(pEl + it * rowskip + cc);
            }
        }

        f16x8 ah[4], bh[4], al[4], bl[4];
        #pragma unroll
        for (int i = 0; i < 4; ++i)
            ah[i] = *(const f16x8*)&sAh[(wrow + i*16 + fr) * LDK + kq];
        #pragma unroll
        for (int j = 0; j < 4; ++j)
            bh[j] = *(const f16x8*)&sBh[(wcol + j*16 + fr) * LDK + kq];
        // hh -> acc
        #pragma unroll
        for (int i = 0; i < 4; ++i)
            #pragma unroll
            for (int j = 0; j < 4; ++j)
                acc[i][j] = __builtin_amdgcn_mfma_f32_16x16x32_f16(ah[i], bh[j], acc[i][j], 0, 0, 0);
        #pragma unroll
        for (int j = 0; j < 4; ++j)
            bl[j] = *(const f16x8*)&sBl[(wcol + j*16 + fr) * LDK + kq];
        // h * sl' -> acr
        #pragma unroll
        for (int i = 0; i < 4; ++i)
            #pragma unroll
            for (int j = 0; j < 4; ++j)
                acr[i][j] = __builtin_amdgcn_mfma_f32_16x16x32_f16(ah[i], bl[j], acr[i][j], 0, 0, 0);
        #pragma unroll
        for (int i = 0; i < 4; ++i)
            al[i] = *(const f16x8*)&sAl[(wrow + i*16 + fr) * LDK + kq];
        // sl * h' -> acr
        #pragma unroll
        for (int i = 0; i < 4; ++i)
            #pragma unroll
            for (int j = 0; j < 4; ++j)
                acr[i][j] = __builtin_amdgcn_mfma_f32_16x16x32_f16(al[i], bh[j], acr[i][j], 0, 0, 0);
    }

    // epilogue: d = xn + en - 2*(hh + cross*2^-12) in f64, rounded to f32
    double ecv[4];
    #pragma unroll
    for (int j = 0; j < 4; ++j) ecv[j] = en[col0 + wcol + j*16 + fr];

    #pragma unroll
    for (int i = 0; i < 4; ++i) {
        int rb = row0 + wrow + i*16 + (lane >> 4) * 4;
        #pragma unroll
        for (int r = 0; r < 4; ++r) {
            double xr = xn[rb + r];
            unsigned long long bk = 0xFFFFFFFFFFFFFFFFull;
            size_t base = (size_t)(rb + r) * K + col0 + wcol + fr;
            #pragma unroll
            for (int j = 0; j < 4; ++j) {
                double dot = (double)acc[i][j][r] + (double)acr[i][j][r] * (1.0 / 4096.0);
                float dv = (float)(xr + ecv[j] - 2.0 * dot);
                dist[base + j*16] = dv;
                unsigned long long kk = ((unsigned long long)fmono(dv) << 32)
                                      | (unsigned)(col0 + wcol + j*16 + fr);
                if (kk < bk) bk = kk;
            }
            #pragma unroll
            for (int o = 1; o < 16; o <<= 1) {
                unsigned long long ot = __shfl_xor(bk, o, 64);
                if (ot < bk) bk = ot;
            }
            if (fr == 0) atomicMin(&keys[rb + r], bk);
        }
    }
}

// ---------------- per-row outputs ----------------
__global__ void row_out(const float* __restrict__ X, const float* __restrict__ E,
                        const unsigned long long* __restrict__ keys,
                        float* __restrict__ quant, float* __restrict__ enc,
                        float* __restrict__ idxf, unsigned int* __restrict__ hist,
                        float* __restrict__ partials, int N, int K)
{
    int wid  = (blockIdx.x * blockDim.x + threadIdx.x) >> 6;
    int lane = threadIdx.x & 63;
    if (wid >= N) return;
    int idx = (int)(unsigned)(keys[wid] & 0xFFFFFFFFull);

    float4 x4 = *(const float4*)(X + (size_t)wid * D + lane*4);
    float4 q4 = *(const float4*)(E + (size_t)idx * D + lane*4);
    *(float4*)(quant + (size_t)wid * D + lane*4) = q4;
    float dx = q4.x-x4.x, dy = q4.y-x4.y, dz = q4.z-x4.z, dw = q4.w-x4.w;
    float s = dx*dx + dy*dy + dz*dz + dw*dw;
    #pragma unroll
    for (int o = 32; o >= 1; o >>= 1) s += __shfl_xor(s, o, 64);

    #pragma unroll
    for (int c = 0; c < 4; ++c) {
        int col = c * 256 + lane * 4;
        float4 v;
        v.x = (col + 0 == idx) ? 1.0f : 0.0f;
        v.y = (col + 1 == idx) ? 1.0f : 0.0f;
        v.z = (col + 2 == idx) ? 1.0f : 0.0f;
        v.w = (col + 3 == idx) ? 1.0f : 0.0f;
        *(float4*)(enc + (size_t)wid * K + col) = v;
    }
    if (lane == 0) {
        partials[wid] = s;
        idxf[wid] = (float)idx;
        atomicAdd(&hist[idx], 1u);
    }
}

// ---------------- finalize ----------------
__global__ void finalize_kernel(const float* __restrict__ partials,
                                const unsigned int* __restrict__ hist,
                                float* __restrict__ out_loss,
                                float* __restrict__ out_perp,
                                int N, int K)
{
    int tid = threadIdx.x;
    float ls = 0.0f;
    for (int i = tid; i < N; i += 1024) ls += partials[i];
    float ent = 0.0f;
    if (tid < K) {
        float p = (float)hist[tid] / (float)N;
        ent = p * logf(p + 1e-10f);
    }
    #pragma unroll
    for (int o = 32; o >= 1; o >>= 1) {
        ls  += __shfl_xor(ls,  o, 64);
        ent += __shfl_xor(ent, o, 64);
    }
    __shared__ float sl[16], se[16];
    int w = tid >> 6, lane = tid & 63;
    if (lane == 0) { sl[w] = ls; se[w] = ent; }
    __syncthreads();
    if (tid == 0) {
        float L = 0.0f, En = 0.0f;
        for (int i = 0; i < 16; ++i) { L += sl[i]; En += se[i]; }
        *out_loss = 0.25f * L / ((float)N * (float)D);
        *out_perp = expf(-En);
    }
}

extern "C" void kernel_launch(void* const* d_in, const int* in_sizes, int n_in,
                              void* d_out, int out_size, void* d_ws, size_t ws_size,
                              hipStream_t stream)
{
    const float* X = (const float*)d_in[0];
    const float* E = (const float*)d_in[1];
    const int N = in_sizes[0] / D;   // 65536
    const int K = in_sizes[1] / D;   // 1024
    float* out = (float*)d_out;

    const size_t O1 = 1;                          // quantized_st  [N*D]
    const size_t O2 = O1 + (size_t)N * D;         // perplexity    [1]
    const size_t O3 = O2 + 1;                     // encodings     [N*K]
    const size_t O4 = O3 + (size_t)N * K;         // distances     [N*K]
    const size_t O5 = O4 + (size_t)N * K;         // indices       [N]

    char* ws = (char*)d_ws;
    size_t off = 0;
    auto alloc = [&](size_t bytes) -> void* {
        void* p = ws + off;
        off += (bytes + 255) & ~(size_t)255;
        return p;
    };
    double* xn = (double*)alloc((size_t)N * 8);
    double* en = (double*)alloc((size_t)K * 8);
    unsigned long long* keys = (unsigned long long*)alloc((size_t)N * 8);
    unsigned int* hist = (unsigned int*)alloc((size_t)K * 4);
    float* partials = (float*)alloc((size_t)N * 4);
    unsigned short* Xh = (unsigned short*)alloc((size_t)N * D * 2);
    unsigned short* Xl = (unsigned short*)alloc((size_t)N * D * 2);
    unsigned short* Eh = (unsigned short*)alloc((size_t)K * D * 2);
    unsigned short* El = (unsigned short*)alloc((size_t)K * D * 2);

    int prep_blocks = (N + K + 3) / 4;
    prep_kernel<<<prep_blocks, 256, 0, stream>>>(X, E, xn, en, Xh, Xl, Eh, El,
                                                 keys, hist, N, K);

    dim3 g(K / BN, N / BM);
    dist_mfma<<<g, 256, 0, stream>>>(Xh, Xl, Eh, El, xn, en,
                                     out + O4, keys, N, K);

    row_out<<<N / 4, 256, 0, stream>>>(X, E, keys, out + O1, out + O3,
                                       out + O5, hist, partials, N, K);

    finalize_kernel<<<1, 1024, 0, stream>>>(partials, hist, out, out + O2, N, K);
}